// Round 5
// baseline (11242.030 us; speedup 1.0000x reference)
//
#include <hip/hip_runtime.h>
#include <stdint.h>

#define DD 256
#define NEDGE 300000
#define NNODE 100000
#define NLAY 9
#define LN_EPS 1e-5f

typedef __attribute__((ext_vector_type(8))) short bf16x8;
typedef __attribute__((ext_vector_type(4))) short s16x4;
typedef __attribute__((ext_vector_type(4))) float f32x4;
typedef __attribute__((ext_vector_type(4))) int i32x4;

static __device__ __forceinline__ short f2bf(float f) {
  union { float f; uint32_t u; } v; v.f = f;
  uint32_t r = (v.u + 0x7FFFu + ((v.u >> 16) & 1u)) >> 16;
  return (short)(uint16_t)r;
}
static __device__ __forceinline__ float bf2f(short s) {
  union { uint32_t u; float f; } v; v.u = ((uint32_t)(uint16_t)s) << 16;
  return v.f;
}

static __device__ __forceinline__ void gld16(const void* g, void* l) {
  __builtin_amdgcn_global_load_lds((const __attribute__((address_space(1))) void*)g,
                                   (__attribute__((address_space(3))) void*)l, 16, 0, 0);
}

// ---------------------------------------------------------------------------
// Fused MLP v5. 256 thr = 4 waves; wave owns 64 output cols, all 64 rows.
// A: DMA-staged one tile ahead (grid-stride, dbuf 2x32KB; hidden aliases the
//    current A buffer after GEMM1). K-loop reads A via swizzled ds_read_b128.
// W: one 32-load register burst per GEMM (L2-resident), reused array W1->W2.
// K-loops have no barriers and no global dependencies.
// LDS: A0 @0, A1 @32768, redbuf @65536 (2KB). Total 67584, 2 blocks/CU.
// ---------------------------------------------------------------------------
template<bool A_BF16, bool NODE>
__global__ __launch_bounds__(256, 2) void mlp_kernel(
    const void* __restrict__ Ain, const int* __restrict__ rowmap,
    const short* __restrict__ W1, const short* __restrict__ W2,
    const float* __restrict__ B1, const float* __restrict__ B2,
    const float* __restrict__ LG, const float* __restrict__ LB,
    short* __restrict__ OutB, float* __restrict__ OutF,
    const float* __restrict__ Resid, short* __restrict__ XbOut, int M) {
  extern __shared__ char smem[];
  float* redbuf = (float*)(smem + 65536);
  const int tid = threadIdx.x;
  const int lane = tid & 63;
  const int wv = tid >> 6;
  const int l15 = lane & 15, lq = lane >> 4;
  const int cbase = wv * 64;
  const int ntiles = (M + 63) >> 6;

  const short* wcol1[4];
  const short* wcol2[4];
  float b1v[4], b2v[4], gv[4], bvv[4];
#pragma unroll
  for (int ni = 0; ni < 4; ++ni) {
    const int c = cbase + ni * 16 + l15;
    wcol1[ni] = W1 + (size_t)c * DD + lq * 8;
    wcol2[ni] = W2 + (size_t)c * DD + lq * 8;
    b1v[ni] = B1[c]; b2v[ni] = B2[c]; gv[ni] = LG[c]; bvv[ni] = LB[c];
  }

  // DMA-stage a 64-row A tile (bf16) into buffer pb2; source pre-swizzled so
  // linear DMA dest == XOR-swizzled layout (involution).
  auto stageA = [&](int tt, int pb2) {
    if constexpr (A_BF16) {
      const int R0 = wv * 16;
      char* base = smem + pb2 * 32768 + R0 * 512;
      const short* A = (const short*)Ain;
#pragma unroll
      for (int i = 0; i < 8; ++i) {
        const int rl = R0 + i * 2 + (lane >> 5);
        const int gr = min(tt * 64 + rl, M - 1);
        const int o = (lane & 31) ^ (rl & 7);
        gld16(A + (size_t)gr * DD + o * 8, base + i * 1024);
      }
    }
  };

  f32x4 acc[4][4];
  const int t0 = blockIdx.x;
  if (t0 < ntiles) stageA(t0, 0);

  int pb = 0;
  for (int t = t0; t < ntiles; t += gridDim.x, pb ^= 1) {
    const int r0 = t * 64;
    __syncthreads();  // (B0) A[pb] ready; prev tile's LDS reads complete
    if (t + (int)gridDim.x < ntiles) stageA(t + gridDim.x, pb ^ 1);

#pragma unroll
    for (int mi = 0; mi < 4; ++mi)
#pragma unroll
      for (int ni = 0; ni < 4; ++ni) acc[mi][ni] = (f32x4){0.f, 0.f, 0.f, 0.f};

    // ---- W1 burst into registers ----
    bf16x8 wf[4][8];
#pragma unroll
    for (int ni = 0; ni < 4; ++ni)
#pragma unroll
      for (int kk = 0; kk < 8; ++kk) wf[ni][kk] = *(const bf16x8*)(wcol1[ni] + kk * 32);

    // ---- GEMM1: h = relu(A @ W1^T + b1); A from LDS, W from regs ----------
    const short* Ash = (const short*)(smem + pb * 32768);
#pragma unroll
    for (int kk = 0; kk < 8; ++kk) {
      bf16x8 a[4];
#pragma unroll
      for (int mi = 0; mi < 4; ++mi) {
        if (A_BF16) {
          a[mi] = *(const bf16x8*)(Ash + (mi * 16 + l15) * 256 +
                                   (((kk * 4 + lq) ^ (l15 & 7)) << 3));
        } else {
          const int ar = min(r0 + mi * 16 + l15, M - 1);
          const float* af = (const float*)Ain + (size_t)(rowmap ? rowmap[ar] : ar) * DD + lq * 8;
          const f32x4 u0 = *(const f32x4*)(af + kk * 32);
          const f32x4 u1 = *(const f32x4*)(af + kk * 32 + 4);
#pragma unroll
          for (int j = 0; j < 4; ++j) { a[mi][j] = f2bf(u0[j]); a[mi][j + 4] = f2bf(u1[j]); }
        }
      }
#pragma unroll
      for (int ni = 0; ni < 4; ++ni)
#pragma unroll
        for (int mi = 0; mi < 4; ++mi)
          acc[mi][ni] = __builtin_amdgcn_mfma_f32_16x16x32_bf16(a[mi], wf[ni][kk], acc[mi][ni], 0, 0, 0);
    }
    __syncthreads();  // (B1) GEMM1 LDS reads done; also next-tile DMA covered

    // ---- epilogue 1: bias+relu -> hidden (aliases A[pb], granule swizzle) --
    short* hidden = (short*)(smem + pb * 32768);
#pragma unroll
    for (int ni = 0; ni < 4; ++ni) {
      const int c = cbase + ni * 16 + l15;
#pragma unroll
      for (int mi = 0; mi < 4; ++mi)
#pragma unroll
        for (int i = 0; i < 4; ++i) {
          const int row = mi * 16 + lq * 4 + i;
          hidden[row * DD + ((((c >> 3) ^ (row & 7))) << 3) + (c & 7)] =
              f2bf(fmaxf(acc[mi][ni][i] + b1v[ni], 0.f));
          acc[mi][ni][i] = 0.f;
        }
    }
    // ---- W2 burst ----
#pragma unroll
    for (int ni = 0; ni < 4; ++ni)
#pragma unroll
      for (int kk = 0; kk < 8; ++kk) wf[ni][kk] = *(const bf16x8*)(wcol2[ni] + kk * 32);
    __syncthreads();  // (B2) hidden ready

    // ---- GEMM2: y = h @ W2^T ----------------------------------------------
#pragma unroll
    for (int kk = 0; kk < 8; ++kk) {
      bf16x8 a[4];
#pragma unroll
      for (int mi = 0; mi < 4; ++mi) {
        const int hr = mi * 16 + l15;
        a[mi] = *(const bf16x8*)(hidden + hr * DD + (((kk * 4 + lq) ^ (hr & 7)) << 3));
      }
#pragma unroll
      for (int ni = 0; ni < 4; ++ni)
#pragma unroll
        for (int mi = 0; mi < 4; ++mi)
          acc[mi][ni] = __builtin_amdgcn_mfma_f32_16x16x32_bf16(a[mi], wf[ni][kk], acc[mi][ni], 0, 0, 0);
    }

    // ---- LayerNorm ----
    float mean_[4][4], inv_[4][4];
#pragma unroll
    for (int mi = 0; mi < 4; ++mi)
#pragma unroll
      for (int i = 0; i < 4; ++i) {
        float s1 = 0.f, s2 = 0.f;
#pragma unroll
        for (int ni = 0; ni < 4; ++ni) {
          const float v = acc[mi][ni][i] + b2v[ni];
          s1 += v; s2 += v * v;
        }
#pragma unroll
        for (int off = 1; off < 16; off <<= 1) {
          s1 += __shfl_xor(s1, off);
          s2 += __shfl_xor(s2, off);
        }
        mean_[mi][i] = s1; inv_[mi][i] = s2;
      }
    if (l15 == 0) {
#pragma unroll
      for (int mi = 0; mi < 4; ++mi)
#pragma unroll
        for (int i = 0; i < 4; ++i) {
          const int row = mi * 16 + lq * 4 + i;
          redbuf[(row * 4 + wv) * 2 + 0] = mean_[mi][i];
          redbuf[(row * 4 + wv) * 2 + 1] = inv_[mi][i];
        }
    }
    __syncthreads();  // (B3) redbuf ready; hidden reads complete
#pragma unroll
    for (int mi = 0; mi < 4; ++mi)
#pragma unroll
      for (int i = 0; i < 4; ++i) {
        const int row = mi * 16 + lq * 4 + i;
        float t1 = 0.f, t2 = 0.f;
#pragma unroll
        for (int w = 0; w < 4; ++w) {
          t1 += redbuf[(row * 4 + w) * 2 + 0];
          t2 += redbuf[(row * 4 + w) * 2 + 1];
        }
        const float mean = t1 * (1.f / 256.f);
        const float var = t2 * (1.f / 256.f) - mean * mean;
        mean_[mi][i] = mean;
        inv_[mi][i] = rsqrtf(var + LN_EPS);
      }

    if (NODE) {
      // two passes of 128 cols through A[pb] region as f32 (32KB)
      float* ob = (float*)(smem + pb * 32768);
#pragma unroll
      for (int h = 0; h < 2; ++h) {
        if ((cbase >> 7) == h) {
#pragma unroll
          for (int ni = 0; ni < 4; ++ni) {
            const int cl = cbase - h * 128 + ni * 16 + l15;
#pragma unroll
            for (int mi = 0; mi < 4; ++mi)
#pragma unroll
              for (int i = 0; i < 4; ++i) {
                const int row = mi * 16 + lq * 4 + i;
                const float y = (acc[mi][ni][i] + b2v[ni] - mean_[mi][i]) * inv_[mi][i] * gv[ni] + bvv[ni];
                ob[row * 128 + (((cl >> 2) ^ (row & 7)) << 2) + (cl & 3)] = y;
              }
          }
        }
        __syncthreads();  // ob(h) ready
#pragma unroll
        for (int j = 0; j < 8; ++j) {
          const int gg = tid + 256 * j;
          const int row = gg >> 5, Lc = gg & 31;
          const int grow = r0 + row;
          if (grow < M) {
            f32x4 v = *(const f32x4*)(ob + row * 128 + ((Lc ^ (row & 7)) << 2));
            const f32x4 xr = *(const f32x4*)(Resid + (size_t)grow * DD + h * 128 + Lc * 4);
            v = v + xr;
            *(f32x4*)(OutF + (size_t)grow * DD + h * 128 + Lc * 4) = v;
            s16x4 o; o.x = f2bf(v.x); o.y = f2bf(v.y); o.z = f2bf(v.z); o.w = f2bf(v.w);
            *(s16x4*)(XbOut + (size_t)grow * DD + h * 128 + Lc * 4) = o;
          }
        }
        if (h == 0) __syncthreads();  // reads done before pass-1 writes
      }
    } else {
      short* ob = hidden;  // reuse region, same swizzle
#pragma unroll
      for (int ni = 0; ni < 4; ++ni) {
        const int c = cbase + ni * 16 + l15;
#pragma unroll
        for (int mi = 0; mi < 4; ++mi)
#pragma unroll
          for (int i = 0; i < 4; ++i) {
            const int row = mi * 16 + lq * 4 + i;
            const float y = (acc[mi][ni][i] + b2v[ni] - mean_[mi][i]) * inv_[mi][i] * gv[ni] + bvv[ni];
            ob[row * DD + (((c >> 3) ^ (row & 7)) << 3) + (c & 7)] = f2bf(y);
          }
      }
      __syncthreads();  // (B4) ob ready
#pragma unroll
      for (int j = 0; j < 8; ++j) {
        const int gg = tid + 256 * j;
        const int row = gg >> 5, Lg = gg & 31;
        const int grow = r0 + row;
        if (grow < M) {
          const i32x4 v = *(const i32x4*)(ob + row * DD + ((Lg ^ (row & 7)) << 3));
          *(i32x4*)(OutB + (size_t)grow * DD + Lg * 8) = v;
        }
      }
    }
  }
}

// ----------------------- aggregation: wave per node, CSR-sorted efeat ------
__global__ __launch_bounds__(256) void aggregate_kernel(
    const short* __restrict__ xb, const short* __restrict__ efs,
    const int* __restrict__ offs, const int* __restrict__ ssrc,
    short* __restrict__ aggr) {
  const int w = (blockIdx.x * blockDim.x + threadIdx.x) >> 6;
  if (w >= NNODE) return;
  const int lane = threadIdx.x & 63;
  const int beg = offs[w], end = offs[w + 1];
  float s0 = 0.f, s1 = 0.f, s2 = 0.f, s3 = 0.f;
  int p = beg;
  for (; p + 3 < end; p += 4) {
    const int a0 = ssrc[p], a1 = ssrc[p + 1], a2 = ssrc[p + 2], a3 = ssrc[p + 3];
    const s16x4 e0 = *(const s16x4*)(efs + (size_t)p * DD + lane * 4);
    const s16x4 e1 = *(const s16x4*)(efs + (size_t)(p + 1) * DD + lane * 4);
    const s16x4 e2 = *(const s16x4*)(efs + (size_t)(p + 2) * DD + lane * 4);
    const s16x4 e3 = *(const s16x4*)(efs + (size_t)(p + 3) * DD + lane * 4);
    const s16x4 x0 = *(const s16x4*)(xb + (size_t)a0 * DD + lane * 4);
    const s16x4 x1 = *(const s16x4*)(xb + (size_t)a1 * DD + lane * 4);
    const s16x4 x2 = *(const s16x4*)(xb + (size_t)a2 * DD + lane * 4);
    const s16x4 x3 = *(const s16x4*)(xb + (size_t)a3 * DD + lane * 4);
    s0 += bf2f(e0.x) + bf2f(x0.x) + bf2f(e1.x) + bf2f(x1.x) +
          bf2f(e2.x) + bf2f(x2.x) + bf2f(e3.x) + bf2f(x3.x);
    s1 += bf2f(e0.y) + bf2f(x0.y) + bf2f(e1.y) + bf2f(x1.y) +
          bf2f(e2.y) + bf2f(x2.y) + bf2f(e3.y) + bf2f(x3.y);
    s2 += bf2f(e0.z) + bf2f(x0.z) + bf2f(e1.z) + bf2f(x1.z) +
          bf2f(e2.z) + bf2f(x2.z) + bf2f(e3.z) + bf2f(x3.z);
    s3 += bf2f(e0.w) + bf2f(x0.w) + bf2f(e1.w) + bf2f(x1.w) +
          bf2f(e2.w) + bf2f(x2.w) + bf2f(e3.w) + bf2f(x3.w);
  }
  for (; p < end; ++p) {
    const s16x4 ev = *(const s16x4*)(efs + (size_t)p * DD + lane * 4);
    const s16x4 xv = *(const s16x4*)(xb + (size_t)ssrc[p] * DD + lane * 4);
    s0 += bf2f(ev.x) + bf2f(xv.x);
    s1 += bf2f(ev.y) + bf2f(xv.y);
    s2 += bf2f(ev.z) + bf2f(xv.z);
    s3 += bf2f(ev.w) + bf2f(xv.w);
  }
  s16x4 o; o.x = f2bf(s0); o.y = f2bf(s1); o.z = f2bf(s2); o.w = f2bf(s3);
  *(s16x4*)(aggr + (size_t)w * DD + lane * 4) = o;
}

__global__ void count_kernel(const int* __restrict__ tgt, int* __restrict__ deg) {
  const int e = blockIdx.x * 256 + threadIdx.x;
  if (e < NEDGE) atomicAdd(&deg[tgt[e]], 1);
}

__global__ __launch_bounds__(1024) void scan_kernel(
    const int* __restrict__ deg, int* __restrict__ offs, int* __restrict__ cur) {
  __shared__ int part[1024];
  const int t = threadIdx.x;
  const int CH = 98;  // 1024*98 >= 100000
  const int base = t * CH;
  int s = 0;
  for (int i = 0; i < CH; ++i) {
    const int idx = base + i;
    if (idx < NNODE) s += deg[idx];
  }
  part[t] = s;
  __syncthreads();
  for (int off = 1; off < 1024; off <<= 1) {
    const int v = (t >= off) ? part[t - off] : 0;
    __syncthreads();
    part[t] += v;
    __syncthreads();
  }
  int run = (t > 0) ? part[t - 1] : 0;  // exclusive prefix
  for (int i = 0; i < CH; ++i) {
    const int idx = base + i;
    if (idx < NNODE) {
      offs[idx] = run;
      cur[idx] = run;
      run += deg[idx];
    }
  }
  if (t == 1023) offs[NNODE] = part[1023];
}

__global__ void fill_kernel(const int* __restrict__ src, const int* __restrict__ tgt,
                            int* cur, int* seid, int* ssrc) {
  const int e = blockIdx.x * 256 + threadIdx.x;
  if (e < NEDGE) {
    const int t = tgt[e];
    const int p = atomicAdd(&cur[t], 1);
    seid[p] = e;
    ssrc[p] = src[e];
  }
}

__global__ void cvt4_kernel(const float* __restrict__ src, short* __restrict__ dst, int n4) {
  for (int i = blockIdx.x * blockDim.x + threadIdx.x; i < n4; i += gridDim.x * blockDim.x) {
    const f32x4 v = ((const f32x4*)src)[i];
    s16x4 o;
    o.x = f2bf(v.x); o.y = f2bf(v.y); o.z = f2bf(v.z); o.w = f2bf(v.w);
    ((s16x4*)dst)[i] = o;
  }
}

// gather rows by perm and convert f32 -> bf16 (wave per row)
__global__ __launch_bounds__(256) void gather_cvt_kernel(
    const float* __restrict__ src, const int* __restrict__ perm,
    short* __restrict__ dst, int n) {
  const int w = (blockIdx.x * blockDim.x + threadIdx.x) >> 6;
  if (w >= n) return;
  const int lane = threadIdx.x & 63;
  const f32x4 v = *(const f32x4*)(src + (size_t)perm[w] * DD + lane * 4);
  s16x4 o; o.x = f2bf(v.x); o.y = f2bf(v.y); o.z = f2bf(v.z); o.w = f2bf(v.w);
  *(s16x4*)(dst + (size_t)w * DD + lane * 4) = o;
}

// ---------------------------------------------------------------------------
extern "C" void kernel_launch(void* const* d_in, const int* in_sizes, int n_in,
                              void* d_out, int out_size, void* d_ws, size_t ws_size,
                              hipStream_t stream) {
  const float* x_in = (const float*)d_in[0];
  const float* ea_f = (const float*)d_in[1];
  const float* e1w = (const float*)d_in[2];
  const float* e1b = (const float*)d_in[3];
  const float* e2w = (const float*)d_in[4];
  const float* e2b = (const float*)d_in[5];
  const float* elg = (const float*)d_in[6];
  const float* elb = (const float*)d_in[7];
  const float* n1w = (const float*)d_in[8];
  const float* n1b = (const float*)d_in[9];
  const float* n2w = (const float*)d_in[10];
  const float* n2b = (const float*)d_in[11];
  const float* nlg = (const float*)d_in[12];
  const float* nlb = (const float*)d_in[13];
  const int* eidx = (const int*)d_in[14];
  float* x = (float*)d_out;

  char* p = (char*)d_ws;
  auto take = [&](size_t bytes) {
    char* r = p;
    p += (bytes + 255) & ~(size_t)255;
    return r;
  };
  short* efeat = (short*)take((size_t)NEDGE * DD * 2);  // sorted-order edge MLP out
  short* aggr = (short*)take((size_t)NNODE * DD * 2);
  short* xb = (short*)take((size_t)NNODE * DD * 2);     // bf16 mirror of x
  short* we1 = (short*)take((size_t)NLAY * DD * DD * 2);
  short* we2 = (short*)take((size_t)NLAY * DD * DD * 2);
  short* wn1 = (short*)take((size_t)NLAY * DD * DD * 2);
  short* wn2 = (short*)take((size_t)NLAY * DD * DD * 2);
  int* deg = (int*)take((size_t)NNODE * 4);
  int* offs = (int*)take((size_t)(NNODE + 1) * 4);
  int* cur = (int*)take((size_t)NNODE * 4);
  int* seid = (int*)take((size_t)NEDGE * 4);
  int* ssrc = (int*)take((size_t)NEDGE * 4);
  short* eab = (short*)take((size_t)NEDGE * DD * 2);    // sorted bf16 edge_attr
  const bool use_eab = ((size_t)(p - (char*)d_ws) <= ws_size);

  const int SMEM = 67584;
  hipFuncSetAttribute((const void*)mlp_kernel<true, false>,
                      hipFuncAttributeMaxDynamicSharedMemorySize, SMEM);
  hipFuncSetAttribute((const void*)mlp_kernel<false, false>,
                      hipFuncAttributeMaxDynamicSharedMemorySize, SMEM);
  hipFuncSetAttribute((const void*)mlp_kernel<true, true>,
                      hipFuncAttributeMaxDynamicSharedMemorySize, SMEM);

  hipMemcpyAsync(x, x_in, (size_t)NNODE * DD * 4, hipMemcpyDeviceToDevice, stream);

  const int wn4 = NLAY * DD * DD / 4;
  cvt4_kernel<<<576, 256, 0, stream>>>(e1w, we1, wn4);
  cvt4_kernel<<<576, 256, 0, stream>>>(e2w, we2, wn4);
  cvt4_kernel<<<576, 256, 0, stream>>>(n1w, wn1, wn4);
  cvt4_kernel<<<576, 256, 0, stream>>>(n2w, wn2, wn4);
  cvt4_kernel<<<2048, 256, 0, stream>>>(x_in, xb, NNODE * DD / 4);

  hipMemsetAsync(deg, 0, (size_t)NNODE * 4, stream);
  count_kernel<<<(NEDGE + 255) / 256, 256, 0, stream>>>(eidx + NEDGE, deg);
  scan_kernel<<<1, 1024, 0, stream>>>(deg, offs, cur);
  fill_kernel<<<(NEDGE + 255) / 256, 256, 0, stream>>>(eidx, eidx + NEDGE, cur, seid, ssrc);
  if (use_eab)
    gather_cvt_kernel<<<NEDGE / 4, 256, 0, stream>>>(ea_f, seid, eab, NEDGE);

  for (int l = 0; l < NLAY; ++l) {
    if (use_eab) {
      mlp_kernel<true, false><<<512, 256, SMEM, stream>>>(
          eab, nullptr, we1 + l * DD * DD, we2 + l * DD * DD, e1b + l * DD,
          e2b + l * DD, elg + l * DD, elb + l * DD, efeat, nullptr, nullptr,
          nullptr, NEDGE);
    } else {
      mlp_kernel<false, false><<<512, 256, SMEM, stream>>>(
          ea_f, seid, we1 + l * DD * DD, we2 + l * DD * DD, e1b + l * DD,
          e2b + l * DD, elg + l * DD, elb + l * DD, efeat, nullptr, nullptr,
          nullptr, NEDGE);
    }
    aggregate_kernel<<<(NNODE * 64 + 255) / 256, 256, 0, stream>>>(xb, efeat, offs, ssrc, aggr);
    mlp_kernel<true, true><<<512, 256, SMEM, stream>>>(
        aggr, nullptr, wn1 + l * DD * DD, wn2 + l * DD * DD, n1b + l * DD,
        n2b + l * DD, nlg + l * DD, nlb + l * DD, nullptr, x, x, xb, NNODE);
  }
  (void)in_sizes; (void)n_in; (void)out_size; (void)ws_size;
}

// Round 6
// 8378.899 us; speedup vs baseline: 1.3417x; 1.3417x over previous
//
#include <hip/hip_runtime.h>
#include <stdint.h>

#define DD 256
#define NEDGE 300000
#define NNODE 100000
#define NLAY 9
#define LN_EPS 1e-5f

typedef __attribute__((ext_vector_type(8))) short bf16x8;
typedef __attribute__((ext_vector_type(4))) short s16x4;
typedef __attribute__((ext_vector_type(4))) float f32x4;
typedef __attribute__((ext_vector_type(4))) int i32x4;

static __device__ __forceinline__ short f2bf(float f) {
  union { float f; uint32_t u; } v; v.f = f;
  uint32_t r = (v.u + 0x7FFFu + ((v.u >> 16) & 1u)) >> 16;
  return (short)(uint16_t)r;
}
static __device__ __forceinline__ float bf2f(short s) {
  union { uint32_t u; float f; } v; v.u = ((uint32_t)(uint16_t)s) << 16;
  return v.f;
}

static __device__ __forceinline__ void gld16(const void* g, void* l) {
  __builtin_amdgcn_global_load_lds((const __attribute__((address_space(1))) void*)g,
                                   (__attribute__((address_space(3))) void*)l, 16, 0, 0);
}

// ---------------------------------------------------------------------------
// Fused MLP v6. 512 thr = 8 waves; wave = 32 rows x 32 cols; tile = 32x256.
// acc = 16 VGPR, per-GEMM hoisted W = 64 VGPR -> total <= 128 VGPR
// => 2 blocks/CU via __launch_bounds__(512,4) => 16 waves/CU (50% occ).
// A: DMA one tile ahead (dbuf 2x16KB, pre-swizzled source, swizzled ds_read).
// K-loops: 2 ds_read_b128 + 4 MFMA per kk; no barriers, no global deps.
// LDS: A0 @0, A1 @16K, hidden @32K (16K), redbuf @48K (2K). 50KB static.
// ---------------------------------------------------------------------------
template<bool A_BF16, bool NODE>
__global__ __launch_bounds__(512, 4) void mlp_kernel(
    const void* __restrict__ Ain, const int* __restrict__ rowmap,
    const short* __restrict__ W1, const short* __restrict__ W2,
    const float* __restrict__ B1, const float* __restrict__ B2,
    const float* __restrict__ LG, const float* __restrict__ LB,
    short* __restrict__ OutB, float* __restrict__ OutF,
    const float* __restrict__ Resid, short* __restrict__ XbOut, int M) {
  __shared__ char smem[51200];
  short* hidden = (short*)(smem + 32768);
  float* redbuf = (float*)(smem + 49152);
  const int tid = threadIdx.x;
  const int lane = tid & 63;
  const int wv = tid >> 6;  // 0..7, col-group of 32
  const int l15 = lane & 15, lq = lane >> 4;
  const int cbase = wv * 32;
  const int ntiles = M >> 5;  // M % 32 == 0 for both edge and node

  int co[2];
  float b1v[2], b2v[2], gv[2], bvv[2];
#pragma unroll
  for (int ni = 0; ni < 2; ++ni) {
    const int c = cbase + ni * 16 + l15;
    co[ni] = c * DD + lq * 8;
    b1v[ni] = B1[c]; b2v[ni] = B2[c]; gv[ni] = LG[c]; bvv[ni] = LB[c];
  }

  // stage one 32-row A tile into buffer pb2 (inverse-swizzled source so that
  // linear DMA dest + swizzled ds_read form the same involution)
  auto stageA = [&](int tt, int pb2) {
    if constexpr (A_BF16) {
      const short* A = (const short*)Ain;
#pragma unroll
      for (int pp = 0; pp < 2; ++pp) {
        const int L = pp * 512 + tid;  // per-lane chunk index (16B chunks)
        const int r = L >> 5;
        const int c8 = (L & 31) ^ (r & 7);
        char* dst = smem + pb2 * 16384 + pp * 8192 + wv * 1024;  // wave-uniform
        gld16(A + (size_t)(tt * 32 + r) * DD + c8 * 8, dst);
      }
    } else {
      const float* A = (const float*)Ain;
#pragma unroll
      for (int pp = 0; pp < 2; ++pp) {
        const int L = pp * 512 + tid;
        const int r = L >> 5;
        const int c8 = (L & 31) ^ (r & 7);
        const int gr = rowmap ? rowmap[tt * 32 + r] : (tt * 32 + r);
        const f32x4 u0 = *(const f32x4*)(A + (size_t)gr * DD + c8 * 8);
        const f32x4 u1 = *(const f32x4*)(A + (size_t)gr * DD + c8 * 8 + 4);
        bf16x8 o;
#pragma unroll
        for (int j = 0; j < 4; ++j) { o[j] = f2bf(u0[j]); o[j + 4] = f2bf(u1[j]); }
        *(bf16x8*)(smem + pb2 * 16384 + (size_t)L * 16) = o;
      }
    }
  };

  const int t0 = blockIdx.x;
  if (t0 < ntiles) stageA(t0, 0);

  int pb = 0;
  for (int t = t0; t < ntiles; t += gridDim.x, pb ^= 1) {
    const int r0 = t * 32;
    __syncthreads();  // B0: A[pb] ready; prev tile's LDS reads done
    if (t + (int)gridDim.x < ntiles) stageA(t + gridDim.x, pb ^ 1);

    // ---- W1 burst (64 VGPR) ----
    bf16x8 wf[2][8];
#pragma unroll
    for (int ni = 0; ni < 2; ++ni)
#pragma unroll
      for (int kk = 0; kk < 8; ++kk) wf[ni][kk] = *(const bf16x8*)(W1 + co[ni] + kk * 32);

    f32x4 acc[2][2];
#pragma unroll
    for (int mi = 0; mi < 2; ++mi)
#pragma unroll
      for (int ni = 0; ni < 2; ++ni) acc[mi][ni] = (f32x4){0.f, 0.f, 0.f, 0.f};

    // ---- GEMM1 ----
    const short* Ash = (const short*)(smem + pb * 16384);
#pragma unroll
    for (int kk = 0; kk < 8; ++kk) {
      bf16x8 a[2];
#pragma unroll
      for (int mi = 0; mi < 2; ++mi)
        a[mi] = *(const bf16x8*)(Ash + (mi * 16 + l15) * DD +
                                 (((kk * 4 + lq) ^ (l15 & 7)) << 3));
#pragma unroll
      for (int ni = 0; ni < 2; ++ni)
#pragma unroll
        for (int mi = 0; mi < 2; ++mi)
          acc[mi][ni] = __builtin_amdgcn_mfma_f32_16x16x32_bf16(a[mi], wf[ni][kk], acc[mi][ni], 0, 0, 0);
    }

    // ---- W2 burst (reuse wf; loads hide under epilogue + barrier) ----
#pragma unroll
    for (int ni = 0; ni < 2; ++ni)
#pragma unroll
      for (int kk = 0; kk < 8; ++kk) wf[ni][kk] = *(const bf16x8*)(W2 + co[ni] + kk * 32);

    // ---- epilogue 1: bias + relu -> hidden (granule-swizzled bf16) ----
#pragma unroll
    for (int ni = 0; ni < 2; ++ni) {
      const int c = cbase + ni * 16 + l15;
#pragma unroll
      for (int mi = 0; mi < 2; ++mi)
#pragma unroll
        for (int i = 0; i < 4; ++i) {
          const int row = mi * 16 + lq * 4 + i;
          hidden[row * DD + ((((c >> 3) ^ (row & 7))) << 3) + (c & 7)] =
              f2bf(fmaxf(acc[mi][ni][i] + b1v[ni], 0.f));
          acc[mi][ni][i] = 0.f;
        }
    }
    __syncthreads();  // B1: hidden ready; next-tile DMA covered by GEMM1+epi

    // ---- GEMM2 ----
#pragma unroll
    for (int kk = 0; kk < 8; ++kk) {
      bf16x8 a[2];
#pragma unroll
      for (int mi = 0; mi < 2; ++mi)
        a[mi] = *(const bf16x8*)(hidden + (mi * 16 + l15) * DD +
                                 (((kk * 4 + lq) ^ (l15 & 7)) << 3));
#pragma unroll
      for (int ni = 0; ni < 2; ++ni)
#pragma unroll
        for (int mi = 0; mi < 2; ++mi)
          acc[mi][ni] = __builtin_amdgcn_mfma_f32_16x16x32_bf16(a[mi], wf[ni][kk], acc[mi][ni], 0, 0, 0);
    }

    // ---- LayerNorm ----
    float mean_[2][4], inv_[2][4];
#pragma unroll
    for (int mi = 0; mi < 2; ++mi)
#pragma unroll
      for (int i = 0; i < 4; ++i) {
        float s1 = 0.f, s2 = 0.f;
#pragma unroll
        for (int ni = 0; ni < 2; ++ni) {
          const float v = acc[mi][ni][i] + b2v[ni];
          s1 += v; s2 += v * v;
        }
#pragma unroll
        for (int off = 1; off < 16; off <<= 1) {
          s1 += __shfl_xor(s1, off);
          s2 += __shfl_xor(s2, off);
        }
        mean_[mi][i] = s1; inv_[mi][i] = s2;
      }
    if (l15 == 0) {
#pragma unroll
      for (int mi = 0; mi < 2; ++mi)
#pragma unroll
        for (int i = 0; i < 4; ++i) {
          const int row = mi * 16 + lq * 4 + i;
          redbuf[(row * 8 + wv) * 2 + 0] = mean_[mi][i];
          redbuf[(row * 8 + wv) * 2 + 1] = inv_[mi][i];
        }
    }
    __syncthreads();  // B2: redbuf ready; all hidden reads done
#pragma unroll
    for (int mi = 0; mi < 2; ++mi)
#pragma unroll
      for (int i = 0; i < 4; ++i) {
        const int row = mi * 16 + lq * 4 + i;
        float t1 = 0.f, t2 = 0.f;
#pragma unroll
        for (int w = 0; w < 8; ++w) {
          t1 += redbuf[(row * 8 + w) * 2 + 0];
          t2 += redbuf[(row * 8 + w) * 2 + 1];
        }
        const float mean = t1 * (1.f / 256.f);
        const float var = t2 * (1.f / 256.f) - mean * mean;
        mean_[mi][i] = mean;
        inv_[mi][i] = rsqrtf(var + LN_EPS);
      }

    if (NODE) {
      // two half-col passes through hidden region as f32 (16KB = 32x128)
      float* ob = (float*)hidden;
#pragma unroll
      for (int h = 0; h < 2; ++h) {
        if ((cbase >> 7) == h) {
#pragma unroll
          for (int ni = 0; ni < 2; ++ni) {
            const int cl = cbase - h * 128 + ni * 16 + l15;
#pragma unroll
            for (int mi = 0; mi < 2; ++mi)
#pragma unroll
              for (int i = 0; i < 4; ++i) {
                const int row = mi * 16 + lq * 4 + i;
                const float y = (acc[mi][ni][i] + b2v[ni] - mean_[mi][i]) * inv_[mi][i] * gv[ni] + bvv[ni];
                ob[row * 128 + (((cl >> 2) ^ (row & 7)) << 2) + (cl & 3)] = y;
              }
          }
        }
        __syncthreads();  // ob(h) ready
#pragma unroll
        for (int j = 0; j < 2; ++j) {
          const int gg = tid + 512 * j;
          const int row = gg >> 5, Lc = gg & 31;
          const int grow = r0 + row;
          f32x4 v = *(const f32x4*)(ob + row * 128 + ((Lc ^ (row & 7)) << 2));
          const f32x4 xr = *(const f32x4*)(Resid + (size_t)grow * DD + h * 128 + Lc * 4);
          v = v + xr;
          *(f32x4*)(OutF + (size_t)grow * DD + h * 128 + Lc * 4) = v;
          s16x4 o; o.x = f2bf(v.x); o.y = f2bf(v.y); o.z = f2bf(v.z); o.w = f2bf(v.w);
          *(s16x4*)(XbOut + (size_t)grow * DD + h * 128 + Lc * 4) = o;
        }
        if (h == 0) __syncthreads();  // reads done before pass-1 writes
      }
    } else {
      short* ob = hidden;  // reuse, same swizzle
#pragma unroll
      for (int ni = 0; ni < 2; ++ni) {
        const int c = cbase + ni * 16 + l15;
#pragma unroll
        for (int mi = 0; mi < 2; ++mi)
#pragma unroll
          for (int i = 0; i < 4; ++i) {
            const int row = mi * 16 + lq * 4 + i;
            const float y = (acc[mi][ni][i] + b2v[ni] - mean_[mi][i]) * inv_[mi][i] * gv[ni] + bvv[ni];
            ob[row * DD + (((c >> 3) ^ (row & 7)) << 3) + (c & 7)] = f2bf(y);
          }
      }
      __syncthreads();  // B3: ob ready
#pragma unroll
      for (int j = 0; j < 2; ++j) {
        const int gg = tid + 512 * j;
        const int row = gg >> 5, Lg = gg & 31;
        const i32x4 v = *(const i32x4*)(ob + row * DD + ((Lg ^ (row & 7)) << 3));
        *(i32x4*)(OutB + (size_t)(r0 + row) * DD + Lg * 8) = v;
      }
    }
  }
}

// ----------------------- aggregation: wave per node, CSR-sorted efeat ------
__global__ __launch_bounds__(256) void aggregate_kernel(
    const short* __restrict__ xb, const short* __restrict__ efs,
    const int* __restrict__ offs, const int* __restrict__ ssrc,
    short* __restrict__ aggr) {
  const int w = (blockIdx.x * blockDim.x + threadIdx.x) >> 6;
  if (w >= NNODE) return;
  const int lane = threadIdx.x & 63;
  const int beg = offs[w], end = offs[w + 1];
  float s0 = 0.f, s1 = 0.f, s2 = 0.f, s3 = 0.f;
  int p = beg;
  for (; p + 3 < end; p += 4) {
    const int a0 = ssrc[p], a1 = ssrc[p + 1], a2 = ssrc[p + 2], a3 = ssrc[p + 3];
    const s16x4 e0 = *(const s16x4*)(efs + (size_t)p * DD + lane * 4);
    const s16x4 e1 = *(const s16x4*)(efs + (size_t)(p + 1) * DD + lane * 4);
    const s16x4 e2 = *(const s16x4*)(efs + (size_t)(p + 2) * DD + lane * 4);
    const s16x4 e3 = *(const s16x4*)(efs + (size_t)(p + 3) * DD + lane * 4);
    const s16x4 x0 = *(const s16x4*)(xb + (size_t)a0 * DD + lane * 4);
    const s16x4 x1 = *(const s16x4*)(xb + (size_t)a1 * DD + lane * 4);
    const s16x4 x2 = *(const s16x4*)(xb + (size_t)a2 * DD + lane * 4);
    const s16x4 x3 = *(const s16x4*)(xb + (size_t)a3 * DD + lane * 4);
    s0 += bf2f(e0.x) + bf2f(x0.x) + bf2f(e1.x) + bf2f(x1.x) +
          bf2f(e2.x) + bf2f(x2.x) + bf2f(e3.x) + bf2f(x3.x);
    s1 += bf2f(e0.y) + bf2f(x0.y) + bf2f(e1.y) + bf2f(x1.y) +
          bf2f(e2.y) + bf2f(x2.y) + bf2f(e3.y) + bf2f(x3.y);
    s2 += bf2f(e0.z) + bf2f(x0.z) + bf2f(e1.z) + bf2f(x1.z) +
          bf2f(e2.z) + bf2f(x2.z) + bf2f(e3.z) + bf2f(x3.z);
    s3 += bf2f(e0.w) + bf2f(x0.w) + bf2f(e1.w) + bf2f(x1.w) +
          bf2f(e2.w) + bf2f(x2.w) + bf2f(e3.w) + bf2f(x3.w);
  }
  for (; p < end; ++p) {
    const s16x4 ev = *(const s16x4*)(efs + (size_t)p * DD + lane * 4);
    const s16x4 xv = *(const s16x4*)(xb + (size_t)ssrc[p] * DD + lane * 4);
    s0 += bf2f(ev.x) + bf2f(xv.x);
    s1 += bf2f(ev.y) + bf2f(xv.y);
    s2 += bf2f(ev.z) + bf2f(xv.z);
    s3 += bf2f(ev.w) + bf2f(xv.w);
  }
  s16x4 o; o.x = f2bf(s0); o.y = f2bf(s1); o.z = f2bf(s2); o.w = f2bf(s3);
  *(s16x4*)(aggr + (size_t)w * DD + lane * 4) = o;
}

__global__ void count_kernel(const int* __restrict__ tgt, int* __restrict__ deg) {
  const int e = blockIdx.x * 256 + threadIdx.x;
  if (e < NEDGE) atomicAdd(&deg[tgt[e]], 1);
}

__global__ __launch_bounds__(1024) void scan_kernel(
    const int* __restrict__ deg, int* __restrict__ offs, int* __restrict__ cur) {
  __shared__ int part[1024];
  const int t = threadIdx.x;
  const int CH = 98;  // 1024*98 >= 100000
  const int base = t * CH;
  int s = 0;
  for (int i = 0; i < CH; ++i) {
    const int idx = base + i;
    if (idx < NNODE) s += deg[idx];
  }
  part[t] = s;
  __syncthreads();
  for (int off = 1; off < 1024; off <<= 1) {
    const int v = (t >= off) ? part[t - off] : 0;
    __syncthreads();
    part[t] += v;
    __syncthreads();
  }
  int run = (t > 0) ? part[t - 1] : 0;  // exclusive prefix
  for (int i = 0; i < CH; ++i) {
    const int idx = base + i;
    if (idx < NNODE) {
      offs[idx] = run;
      cur[idx] = run;
      run += deg[idx];
    }
  }
  if (t == 1023) offs[NNODE] = part[1023];
}

__global__ void fill_kernel(const int* __restrict__ src, const int* __restrict__ tgt,
                            int* cur, int* seid, int* ssrc) {
  const int e = blockIdx.x * 256 + threadIdx.x;
  if (e < NEDGE) {
    const int t = tgt[e];
    const int p = atomicAdd(&cur[t], 1);
    seid[p] = e;
    ssrc[p] = src[e];
  }
}

__global__ void cvt4_kernel(const float* __restrict__ src, short* __restrict__ dst, int n4) {
  for (int i = blockIdx.x * blockDim.x + threadIdx.x; i < n4; i += gridDim.x * blockDim.x) {
    const f32x4 v = ((const f32x4*)src)[i];
    s16x4 o;
    o.x = f2bf(v.x); o.y = f2bf(v.y); o.z = f2bf(v.z); o.w = f2bf(v.w);
    ((s16x4*)dst)[i] = o;
  }
}

// gather rows by perm and convert f32 -> bf16 (wave per row)
__global__ __launch_bounds__(256) void gather_cvt_kernel(
    const float* __restrict__ src, const int* __restrict__ perm,
    short* __restrict__ dst, int n) {
  const int w = (blockIdx.x * blockDim.x + threadIdx.x) >> 6;
  if (w >= n) return;
  const int lane = threadIdx.x & 63;
  const f32x4 v = *(const f32x4*)(src + (size_t)perm[w] * DD + lane * 4);
  s16x4 o; o.x = f2bf(v.x); o.y = f2bf(v.y); o.z = f2bf(v.z); o.w = f2bf(v.w);
  *(s16x4*)(dst + (size_t)w * DD + lane * 4) = o;
}

// ---------------------------------------------------------------------------
extern "C" void kernel_launch(void* const* d_in, const int* in_sizes, int n_in,
                              void* d_out, int out_size, void* d_ws, size_t ws_size,
                              hipStream_t stream) {
  const float* x_in = (const float*)d_in[0];
  const float* ea_f = (const float*)d_in[1];
  const float* e1w = (const float*)d_in[2];
  const float* e1b = (const float*)d_in[3];
  const float* e2w = (const float*)d_in[4];
  const float* e2b = (const float*)d_in[5];
  const float* elg = (const float*)d_in[6];
  const float* elb = (const float*)d_in[7];
  const float* n1w = (const float*)d_in[8];
  const float* n1b = (const float*)d_in[9];
  const float* n2w = (const float*)d_in[10];
  const float* n2b = (const float*)d_in[11];
  const float* nlg = (const float*)d_in[12];
  const float* nlb = (const float*)d_in[13];
  const int* eidx = (const int*)d_in[14];
  float* x = (float*)d_out;

  char* p = (char*)d_ws;
  auto take = [&](size_t bytes) {
    char* r = p;
    p += (bytes + 255) & ~(size_t)255;
    return r;
  };
  short* efeat = (short*)take((size_t)NEDGE * DD * 2);  // sorted-order edge MLP out
  short* aggr = (short*)take((size_t)NNODE * DD * 2);
  short* xb = (short*)take((size_t)NNODE * DD * 2);     // bf16 mirror of x
  short* we1 = (short*)take((size_t)NLAY * DD * DD * 2);
  short* we2 = (short*)take((size_t)NLAY * DD * DD * 2);
  short* wn1 = (short*)take((size_t)NLAY * DD * DD * 2);
  short* wn2 = (short*)take((size_t)NLAY * DD * DD * 2);
  int* deg = (int*)take((size_t)NNODE * 4);
  int* offs = (int*)take((size_t)(NNODE + 1) * 4);
  int* cur = (int*)take((size_t)NNODE * 4);
  int* seid = (int*)take((size_t)NEDGE * 4);
  int* ssrc = (int*)take((size_t)NEDGE * 4);
  short* eab = (short*)take((size_t)NEDGE * DD * 2);    // sorted bf16 edge_attr
  const bool use_eab = ((size_t)(p - (char*)d_ws) <= ws_size);

  hipMemcpyAsync(x, x_in, (size_t)NNODE * DD * 4, hipMemcpyDeviceToDevice, stream);

  const int wn4 = NLAY * DD * DD / 4;
  cvt4_kernel<<<576, 256, 0, stream>>>(e1w, we1, wn4);
  cvt4_kernel<<<576, 256, 0, stream>>>(e2w, we2, wn4);
  cvt4_kernel<<<576, 256, 0, stream>>>(n1w, wn1, wn4);
  cvt4_kernel<<<576, 256, 0, stream>>>(n2w, wn2, wn4);
  cvt4_kernel<<<2048, 256, 0, stream>>>(x_in, xb, NNODE * DD / 4);

  hipMemsetAsync(deg, 0, (size_t)NNODE * 4, stream);
  count_kernel<<<(NEDGE + 255) / 256, 256, 0, stream>>>(eidx + NEDGE, deg);
  scan_kernel<<<1, 1024, 0, stream>>>(deg, offs, cur);
  fill_kernel<<<(NEDGE + 255) / 256, 256, 0, stream>>>(eidx, eidx + NEDGE, cur, seid, ssrc);
  if (use_eab)
    gather_cvt_kernel<<<NEDGE / 4, 256, 0, stream>>>(ea_f, seid, eab, NEDGE);

  for (int l = 0; l < NLAY; ++l) {
    if (use_eab) {
      mlp_kernel<true, false><<<2048, 512, 0, stream>>>(
          eab, nullptr, we1 + l * DD * DD, we2 + l * DD * DD, e1b + l * DD,
          e2b + l * DD, elg + l * DD, elb + l * DD, efeat, nullptr, nullptr,
          nullptr, NEDGE);
    } else {
      mlp_kernel<false, false><<<2048, 512, 0, stream>>>(
          ea_f, seid, we1 + l * DD * DD, we2 + l * DD * DD, e1b + l * DD,
          e2b + l * DD, elg + l * DD, elb + l * DD, efeat, nullptr, nullptr,
          nullptr, NEDGE);
    }
    aggregate_kernel<<<(NNODE * 64 + 255) / 256, 256, 0, stream>>>(xb, efeat, offs, ssrc, aggr);
    mlp_kernel<true, true><<<2048, 512, 0, stream>>>(
        aggr, nullptr, wn1 + l * DD * DD, wn2 + l * DD * DD, n1b + l * DD,
        n2b + l * DD, nlg + l * DD, nlb + l * DD, nullptr, x, x, xb, NNODE);
  }
  (void)in_sizes; (void)n_in; (void)out_size; (void)ws_size;
}

// Round 7
// 4664.186 us; speedup vs baseline: 2.4103x; 1.7964x over previous
//
#include <hip/hip_runtime.h>
#include <stdint.h>

#define DD 256
#define NEDGE 300000
#define NNODE 100000
#define NLAY 9
#define LN_EPS 1e-5f

typedef __attribute__((ext_vector_type(8))) short bf16x8;
typedef __attribute__((ext_vector_type(4))) short s16x4;
typedef __attribute__((ext_vector_type(4))) float f32x4;
typedef __attribute__((ext_vector_type(4))) int i32x4;

static __device__ __forceinline__ short f2bf(float f) {
  union { float f; uint32_t u; } v; v.f = f;
  uint32_t r = (v.u + 0x7FFFu + ((v.u >> 16) & 1u)) >> 16;
  return (short)(uint16_t)r;
}
static __device__ __forceinline__ float bf2f(short s) {
  union { uint32_t u; float f; } v; v.u = ((uint32_t)(uint16_t)s) << 16;
  return v.f;
}

static __device__ __forceinline__ void gld16(const void* g, void* l) {
  __builtin_amdgcn_global_load_lds((const __attribute__((address_space(1))) void*)g,
                                   (__attribute__((address_space(3))) void*)l, 16, 0, 0);
}

// ---------------------------------------------------------------------------
// Fused MLP v7 — m97-style staged GEMMs.
// 256 thr = 4 waves; tile 64 rows x 256 cols; wave = 64x64 (acc[4][4]).
// Per K-step (BK=32): stage A(4KB)+W(16KB) via global_load_lds into dbuf
// slot (2x20KB), ONE barrier per K-step (stage issued at top, drained by the
// publishing barrier; latency covered by 8 ds_read_b128 + 16 MFMA).
// W never touches registers persistently (spill lesson R3/R5/R6).
// LDS: slot0 @0, slot1 @20480 (each: A @+0 [4][64][16B], W @+4096 [4][256][16B]),
//      hidden @40960 (32KB, granule-swizzled), redbuf @73728. Total 75776.
// ---------------------------------------------------------------------------
template<bool A_BF16, bool NODE>
__global__ __launch_bounds__(256, 2) void mlp_kernel(
    const void* __restrict__ Ain, const int* __restrict__ rowmap,
    const short* __restrict__ W1, const short* __restrict__ W2,
    const float* __restrict__ B1, const float* __restrict__ B2,
    const float* __restrict__ LG, const float* __restrict__ LB,
    short* __restrict__ OutB, float* __restrict__ OutF,
    const float* __restrict__ Resid, short* __restrict__ XbOut, int M) {
  extern __shared__ char smem[];
  short* hidden = (short*)(smem + 40960);
  float* redbuf = (float*)(smem + 73728);
  const int tid = threadIdx.x;
  const int lane = tid & 63;
  const int wv = tid >> 6;
  const int l15 = lane & 15, lq = lane >> 4;
  const int cbase = wv * 64;
  const int r0 = blockIdx.x * 64;

  // A stage chunk: chunk index == tid -> q = tid>>6, r = tid&63
  const int aq = tid >> 6, ar = tid & 63;
  const int agr = min(r0 + ar, M - 1);

  // stage W K-slice k into slot's W region: chunk (q=i, c=tid)
  auto stageW = [&](const short* W, int k, int slot) {
    char* wb = smem + slot * 20480 + 4096;
    const short* src = W + (size_t)tid * DD + k * 32;
#pragma unroll
    for (int i = 0; i < 4; ++i) gld16(src + i * 8, wb + i * 4096 + tid * 16);
  };
  // stage A K-slice k into slot's A region
  auto stageA = [&](int k, int slot) {
    char* ab = smem + slot * 20480;
    if constexpr (A_BF16) {
      const short* src = (const short*)Ain + (size_t)agr * DD + k * 32 + aq * 8;
      gld16(src, ab + tid * 16);
    } else {
      const int gr = rowmap ? rowmap[agr] : agr;
      const float* src = (const float*)Ain + (size_t)gr * DD + k * 32 + aq * 8;
      const f32x4 u0 = *(const f32x4*)(src);
      const f32x4 u1 = *(const f32x4*)(src + 4);
      bf16x8 o;
#pragma unroll
      for (int j = 0; j < 4; ++j) { o[j] = f2bf(u0[j]); o[j + 4] = f2bf(u1[j]); }
      *(bf16x8*)(ab + tid * 16) = o;
    }
  };

  float b1v[4], b2v[4], gv[4], bvv[4];
#pragma unroll
  for (int ni = 0; ni < 4; ++ni) {
    const int c = cbase + ni * 16 + l15;
    b1v[ni] = B1[c]; b2v[ni] = B2[c]; gv[ni] = LG[c]; bvv[ni] = LB[c];
  }

  f32x4 acc[4][4];
#pragma unroll
  for (int mi = 0; mi < 4; ++mi)
#pragma unroll
    for (int ni = 0; ni < 4; ++ni) acc[mi][ni] = (f32x4){0.f, 0.f, 0.f, 0.f};

  // ---------------- GEMM1: h = relu(A @ W1^T + b1) -------------------------
  stageA(0, 0);
  stageW(W1, 0, 0);
  __syncthreads();  // slot0 ready
#pragma unroll
  for (int s = 0; s < 8; ++s) {
    if (s < 7) {
      stageA(s + 1, (s + 1) & 1);
      stageW(W1, s + 1, (s + 1) & 1);
    } else {
      stageW(W2, 0, 0);  // slot0 free (last read at s=6, synced)
    }
    const char* ab = smem + (s & 1) * 20480;
    bf16x8 a[4], b[4];
#pragma unroll
    for (int mi = 0; mi < 4; ++mi)
      a[mi] = *(const bf16x8*)(ab + lq * 1024 + (mi * 16 + l15) * 16);
#pragma unroll
    for (int ni = 0; ni < 4; ++ni)
      b[ni] = *(const bf16x8*)(ab + 4096 + lq * 4096 + (cbase + ni * 16 + l15) * 16);
#pragma unroll
    for (int ni = 0; ni < 4; ++ni)
#pragma unroll
      for (int mi = 0; mi < 4; ++mi)
        acc[mi][ni] = __builtin_amdgcn_mfma_f32_16x16x32_bf16(a[mi], b[ni], acc[mi][ni], 0, 0, 0);
    __syncthreads();  // publish slot[(s+1)&1] (drains stage), guard reuse
  }

  // ---- epilogue 1: bias + relu -> hidden (granule-swizzled bf16) ----------
#pragma unroll
  for (int ni = 0; ni < 4; ++ni) {
    const int c = cbase + ni * 16 + l15;
#pragma unroll
    for (int mi = 0; mi < 4; ++mi)
#pragma unroll
      for (int i = 0; i < 4; ++i) {
        const int row = mi * 16 + lq * 4 + i;
        hidden[row * DD + ((((c >> 3) ^ (row & 7))) << 3) + (c & 7)] =
            f2bf(fmaxf(acc[mi][ni][i] + b1v[ni], 0.f));
        acc[mi][ni][i] = 0.f;
      }
  }
  __syncthreads();  // hidden ready; W2 step0 (staged at s=7) already drained

  // ---------------- GEMM2: y = h @ W2^T ------------------------------------
#pragma unroll
  for (int s = 0; s < 8; ++s) {
    if (s < 7) stageW(W2, s + 1, (s + 1) & 1);
    const char* ab = smem + (s & 1) * 20480;
    bf16x8 a[4], b[4];
#pragma unroll
    for (int mi = 0; mi < 4; ++mi) {
      const int hr = mi * 16 + l15;
      a[mi] = *(const bf16x8*)(hidden + hr * DD + (((s * 4 + lq) ^ (hr & 7)) << 3));
    }
#pragma unroll
    for (int ni = 0; ni < 4; ++ni)
      b[ni] = *(const bf16x8*)(ab + 4096 + lq * 4096 + (cbase + ni * 16 + l15) * 16);
#pragma unroll
    for (int ni = 0; ni < 4; ++ni)
#pragma unroll
      for (int mi = 0; mi < 4; ++mi)
        acc[mi][ni] = __builtin_amdgcn_mfma_f32_16x16x32_bf16(a[mi], b[ni], acc[mi][ni], 0, 0, 0);
    __syncthreads();
  }

  // ---------------- LayerNorm ----------------
  float mean_[4][4], inv_[4][4];
#pragma unroll
  for (int mi = 0; mi < 4; ++mi)
#pragma unroll
    for (int i = 0; i < 4; ++i) {
      float s1 = 0.f, s2 = 0.f;
#pragma unroll
      for (int ni = 0; ni < 4; ++ni) {
        const float v = acc[mi][ni][i] + b2v[ni];
        s1 += v; s2 += v * v;
      }
#pragma unroll
      for (int off = 1; off < 16; off <<= 1) {
        s1 += __shfl_xor(s1, off);
        s2 += __shfl_xor(s2, off);
      }
      mean_[mi][i] = s1; inv_[mi][i] = s2;
    }
  if (l15 == 0) {
#pragma unroll
    for (int mi = 0; mi < 4; ++mi)
#pragma unroll
      for (int i = 0; i < 4; ++i) {
        const int row = mi * 16 + lq * 4 + i;
        redbuf[(row * 4 + wv) * 2 + 0] = mean_[mi][i];
        redbuf[(row * 4 + wv) * 2 + 1] = inv_[mi][i];
      }
  }
  __syncthreads();  // redbuf ready; hidden reads complete
#pragma unroll
  for (int mi = 0; mi < 4; ++mi)
#pragma unroll
    for (int i = 0; i < 4; ++i) {
      const int row = mi * 16 + lq * 4 + i;
      float t1 = 0.f, t2 = 0.f;
#pragma unroll
      for (int w = 0; w < 4; ++w) {
        t1 += redbuf[(row * 4 + w) * 2 + 0];
        t2 += redbuf[(row * 4 + w) * 2 + 1];
      }
      const float mean = t1 * (1.f / 256.f);
      const float var = t2 * (1.f / 256.f) - mean * mean;
      mean_[mi][i] = mean;
      inv_[mi][i] = rsqrtf(var + LN_EPS);
    }

  if (NODE) {
    // two passes of 128 cols through hidden region as f32 (32KB)
    float* ob = (float*)hidden;
#pragma unroll
    for (int h = 0; h < 2; ++h) {
      if ((cbase >> 7) == h) {
#pragma unroll
        for (int ni = 0; ni < 4; ++ni) {
          const int cl = cbase - h * 128 + ni * 16 + l15;
#pragma unroll
          for (int mi = 0; mi < 4; ++mi)
#pragma unroll
            for (int i = 0; i < 4; ++i) {
              const int row = mi * 16 + lq * 4 + i;
              const float y = (acc[mi][ni][i] + b2v[ni] - mean_[mi][i]) * inv_[mi][i] * gv[ni] + bvv[ni];
              ob[row * 128 + (((cl >> 2) ^ (row & 7)) << 2) + (cl & 3)] = y;
            }
        }
      }
      __syncthreads();  // ob(h) ready
#pragma unroll
      for (int j = 0; j < 8; ++j) {
        const int gg = tid + 256 * j;
        const int row = gg >> 5, Lc = gg & 31;
        const int grow = r0 + row;
        if (grow < M) {
          f32x4 v = *(const f32x4*)(ob + row * 128 + ((Lc ^ (row & 7)) << 2));
          const f32x4 xr = *(const f32x4*)(Resid + (size_t)grow * DD + h * 128 + Lc * 4);
          v = v + xr;
          *(f32x4*)(OutF + (size_t)grow * DD + h * 128 + Lc * 4) = v;
          s16x4 o; o.x = f2bf(v.x); o.y = f2bf(v.y); o.z = f2bf(v.z); o.w = f2bf(v.w);
          *(s16x4*)(XbOut + (size_t)grow * DD + h * 128 + Lc * 4) = o;
        }
      }
      if (h == 0) __syncthreads();  // reads done before pass-1 writes
    }
  } else {
    short* ob = hidden;  // reuse region, same swizzle
#pragma unroll
    for (int ni = 0; ni < 4; ++ni) {
      const int c = cbase + ni * 16 + l15;
#pragma unroll
      for (int mi = 0; mi < 4; ++mi)
#pragma unroll
        for (int i = 0; i < 4; ++i) {
          const int row = mi * 16 + lq * 4 + i;
          const float y = (acc[mi][ni][i] + b2v[ni] - mean_[mi][i]) * inv_[mi][i] * gv[ni] + bvv[ni];
          ob[row * DD + (((c >> 3) ^ (row & 7)) << 3) + (c & 7)] = f2bf(y);
        }
    }
    __syncthreads();  // ob ready
#pragma unroll
    for (int j = 0; j < 8; ++j) {
      const int gg = tid + 256 * j;
      const int row = gg >> 5, Lg = gg & 31;
      const int grow = r0 + row;
      if (grow < M) {
        const i32x4 v = *(const i32x4*)(ob + row * DD + ((Lg ^ (row & 7)) << 3));
        *(i32x4*)(OutB + (size_t)grow * DD + Lg * 8) = v;
      }
    }
  }
}

// ----------------------- aggregation: wave per node, CSR-sorted efeat ------
__global__ __launch_bounds__(256) void aggregate_kernel(
    const short* __restrict__ xb, const short* __restrict__ efs,
    const int* __restrict__ offs, const int* __restrict__ ssrc,
    short* __restrict__ aggr) {
  const int w = (blockIdx.x * blockDim.x + threadIdx.x) >> 6;
  if (w >= NNODE) return;
  const int lane = threadIdx.x & 63;
  const int beg = offs[w], end = offs[w + 1];
  float s0 = 0.f, s1 = 0.f, s2 = 0.f, s3 = 0.f;
  int p = beg;
  for (; p + 3 < end; p += 4) {
    const int a0 = ssrc[p], a1 = ssrc[p + 1], a2 = ssrc[p + 2], a3 = ssrc[p + 3];
    const s16x4 e0 = *(const s16x4*)(efs + (size_t)p * DD + lane * 4);
    const s16x4 e1 = *(const s16x4*)(efs + (size_t)(p + 1) * DD + lane * 4);
    const s16x4 e2 = *(const s16x4*)(efs + (size_t)(p + 2) * DD + lane * 4);
    const s16x4 e3 = *(const s16x4*)(efs + (size_t)(p + 3) * DD + lane * 4);
    const s16x4 x0 = *(const s16x4*)(xb + (size_t)a0 * DD + lane * 4);
    const s16x4 x1 = *(const s16x4*)(xb + (size_t)a1 * DD + lane * 4);
    const s16x4 x2 = *(const s16x4*)(xb + (size_t)a2 * DD + lane * 4);
    const s16x4 x3 = *(const s16x4*)(xb + (size_t)a3 * DD + lane * 4);
    s0 += bf2f(e0.x) + bf2f(x0.x) + bf2f(e1.x) + bf2f(x1.x) +
          bf2f(e2.x) + bf2f(x2.x) + bf2f(e3.x) + bf2f(x3.x);
    s1 += bf2f(e0.y) + bf2f(x0.y) + bf2f(e1.y) + bf2f(x1.y) +
          bf2f(e2.y) + bf2f(x2.y) + bf2f(e3.y) + bf2f(x3.y);
    s2 += bf2f(e0.z) + bf2f(x0.z) + bf2f(e1.z) + bf2f(x1.z) +
          bf2f(e2.z) + bf2f(x2.z) + bf2f(e3.z) + bf2f(x3.z);
    s3 += bf2f(e0.w) + bf2f(x0.w) + bf2f(e1.w) + bf2f(x1.w) +
          bf2f(e2.w) + bf2f(x2.w) + bf2f(e3.w) + bf2f(x3.w);
  }
  for (; p < end; ++p) {
    const s16x4 ev = *(const s16x4*)(efs + (size_t)p * DD + lane * 4);
    const s16x4 xv = *(const s16x4*)(xb + (size_t)ssrc[p] * DD + lane * 4);
    s0 += bf2f(ev.x) + bf2f(xv.x);
    s1 += bf2f(ev.y) + bf2f(xv.y);
    s2 += bf2f(ev.z) + bf2f(xv.z);
    s3 += bf2f(ev.w) + bf2f(xv.w);
  }
  s16x4 o; o.x = f2bf(s0); o.y = f2bf(s1); o.z = f2bf(s2); o.w = f2bf(s3);
  *(s16x4*)(aggr + (size_t)w * DD + lane * 4) = o;
}

__global__ void count_kernel(const int* __restrict__ tgt, int* __restrict__ deg) {
  const int e = blockIdx.x * 256 + threadIdx.x;
  if (e < NEDGE) atomicAdd(&deg[tgt[e]], 1);
}

__global__ __launch_bounds__(1024) void scan_kernel(
    const int* __restrict__ deg, int* __restrict__ offs, int* __restrict__ cur) {
  __shared__ int part[1024];
  const int t = threadIdx.x;
  const int CH = 98;  // 1024*98 >= 100000
  const int base = t * CH;
  int s = 0;
  for (int i = 0; i < CH; ++i) {
    const int idx = base + i;
    if (idx < NNODE) s += deg[idx];
  }
  part[t] = s;
  __syncthreads();
  for (int off = 1; off < 1024; off <<= 1) {
    const int v = (t >= off) ? part[t - off] : 0;
    __syncthreads();
    part[t] += v;
    __syncthreads();
  }
  int run = (t > 0) ? part[t - 1] : 0;  // exclusive prefix
  for (int i = 0; i < CH; ++i) {
    const int idx = base + i;
    if (idx < NNODE) {
      offs[idx] = run;
      cur[idx] = run;
      run += deg[idx];
    }
  }
  if (t == 1023) offs[NNODE] = part[1023];
}

__global__ void fill_kernel(const int* __restrict__ src, const int* __restrict__ tgt,
                            int* cur, int* seid, int* ssrc) {
  const int e = blockIdx.x * 256 + threadIdx.x;
  if (e < NEDGE) {
    const int t = tgt[e];
    const int p = atomicAdd(&cur[t], 1);
    seid[p] = e;
    ssrc[p] = src[e];
  }
}

__global__ void cvt4_kernel(const float* __restrict__ src, short* __restrict__ dst, int n4) {
  for (int i = blockIdx.x * blockDim.x + threadIdx.x; i < n4; i += gridDim.x * blockDim.x) {
    const f32x4 v = ((const f32x4*)src)[i];
    s16x4 o;
    o.x = f2bf(v.x); o.y = f2bf(v.y); o.z = f2bf(v.z); o.w = f2bf(v.w);
    ((s16x4*)dst)[i] = o;
  }
}

// gather rows by perm and convert f32 -> bf16 (wave per row)
__global__ __launch_bounds__(256) void gather_cvt_kernel(
    const float* __restrict__ src, const int* __restrict__ perm,
    short* __restrict__ dst, int n) {
  const int w = (blockIdx.x * blockDim.x + threadIdx.x) >> 6;
  if (w >= n) return;
  const int lane = threadIdx.x & 63;
  const f32x4 v = *(const f32x4*)(src + (size_t)perm[w] * DD + lane * 4);
  s16x4 o; o.x = f2bf(v.x); o.y = f2bf(v.y); o.z = f2bf(v.z); o.w = f2bf(v.w);
  *(s16x4*)(dst + (size_t)w * DD + lane * 4) = o;
}

// ---------------------------------------------------------------------------
extern "C" void kernel_launch(void* const* d_in, const int* in_sizes, int n_in,
                              void* d_out, int out_size, void* d_ws, size_t ws_size,
                              hipStream_t stream) {
  const float* x_in = (const float*)d_in[0];
  const float* ea_f = (const float*)d_in[1];
  const float* e1w = (const float*)d_in[2];
  const float* e1b = (const float*)d_in[3];
  const float* e2w = (const float*)d_in[4];
  const float* e2b = (const float*)d_in[5];
  const float* elg = (const float*)d_in[6];
  const float* elb = (const float*)d_in[7];
  const float* n1w = (const float*)d_in[8];
  const float* n1b = (const float*)d_in[9];
  const float* n2w = (const float*)d_in[10];
  const float* n2b = (const float*)d_in[11];
  const float* nlg = (const float*)d_in[12];
  const float* nlb = (const float*)d_in[13];
  const int* eidx = (const int*)d_in[14];
  float* x = (float*)d_out;

  char* p = (char*)d_ws;
  auto take = [&](size_t bytes) {
    char* r = p;
    p += (bytes + 255) & ~(size_t)255;
    return r;
  };
  short* efeat = (short*)take((size_t)NEDGE * DD * 2);  // sorted-order edge MLP out
  short* aggr = (short*)take((size_t)NNODE * DD * 2);
  short* xb = (short*)take((size_t)NNODE * DD * 2);     // bf16 mirror of x
  short* we1 = (short*)take((size_t)NLAY * DD * DD * 2);
  short* we2 = (short*)take((size_t)NLAY * DD * DD * 2);
  short* wn1 = (short*)take((size_t)NLAY * DD * DD * 2);
  short* wn2 = (short*)take((size_t)NLAY * DD * DD * 2);
  int* deg = (int*)take((size_t)NNODE * 4);
  int* offs = (int*)take((size_t)(NNODE + 1) * 4);
  int* cur = (int*)take((size_t)NNODE * 4);
  int* seid = (int*)take((size_t)NEDGE * 4);
  int* ssrc = (int*)take((size_t)NEDGE * 4);
  short* eab = (short*)take((size_t)NEDGE * DD * 2);    // sorted bf16 edge_attr
  const bool use_eab = ((size_t)(p - (char*)d_ws) <= ws_size);

  const int SMEM = 75776;
  hipFuncSetAttribute((const void*)mlp_kernel<true, false>,
                      hipFuncAttributeMaxDynamicSharedMemorySize, SMEM);
  hipFuncSetAttribute((const void*)mlp_kernel<false, false>,
                      hipFuncAttributeMaxDynamicSharedMemorySize, SMEM);
  hipFuncSetAttribute((const void*)mlp_kernel<true, true>,
                      hipFuncAttributeMaxDynamicSharedMemorySize, SMEM);

  hipMemcpyAsync(x, x_in, (size_t)NNODE * DD * 4, hipMemcpyDeviceToDevice, stream);

  const int wn4 = NLAY * DD * DD / 4;
  cvt4_kernel<<<576, 256, 0, stream>>>(e1w, we1, wn4);
  cvt4_kernel<<<576, 256, 0, stream>>>(e2w, we2, wn4);
  cvt4_kernel<<<576, 256, 0, stream>>>(n1w, wn1, wn4);
  cvt4_kernel<<<576, 256, 0, stream>>>(n2w, wn2, wn4);
  cvt4_kernel<<<2048, 256, 0, stream>>>(x_in, xb, NNODE * DD / 4);

  hipMemsetAsync(deg, 0, (size_t)NNODE * 4, stream);
  count_kernel<<<(NEDGE + 255) / 256, 256, 0, stream>>>(eidx + NEDGE, deg);
  scan_kernel<<<1, 1024, 0, stream>>>(deg, offs, cur);
  fill_kernel<<<(NEDGE + 255) / 256, 256, 0, stream>>>(eidx, eidx + NEDGE, cur, seid, ssrc);
  if (use_eab)
    gather_cvt_kernel<<<NEDGE / 4, 256, 0, stream>>>(ea_f, seid, eab, NEDGE);

  const int egrid = (NEDGE + 63) / 64;
  const int ngrid = (NNODE + 63) / 64;
  for (int l = 0; l < NLAY; ++l) {
    if (use_eab) {
      mlp_kernel<true, false><<<egrid, 256, SMEM, stream>>>(
          eab, nullptr, we1 + l * DD * DD, we2 + l * DD * DD, e1b + l * DD,
          e2b + l * DD, elg + l * DD, elb + l * DD, efeat, nullptr, nullptr,
          nullptr, NEDGE);
    } else {
      mlp_kernel<false, false><<<egrid, 256, SMEM, stream>>>(
          ea_f, seid, we1 + l * DD * DD, we2 + l * DD * DD, e1b + l * DD,
          e2b + l * DD, elg + l * DD, elb + l * DD, efeat, nullptr, nullptr,
          nullptr, NEDGE);
    }
    aggregate_kernel<<<(NNODE * 64 + 255) / 256, 256, 0, stream>>>(xb, efeat, offs, ssrc, aggr);
    mlp_kernel<true, true><<<ngrid, 256, SMEM, stream>>>(
        aggr, nullptr, wn1 + l * DD * DD, wn2 + l * DD * DD, n1b + l * DD,
        n2b + l * DD, nlg + l * DD, nlb + l * DD, nullptr, x, x, xb, NNODE);
  }
  (void)in_sizes; (void)n_in; (void)out_size; (void)ws_size;
}